// Round 3
// baseline (119.737 us; speedup 1.0000x reference)
//
#include <hip/hip_runtime.h>
#include <hip/hip_bf16.h>

typedef __attribute__((ext_vector_type(4))) float f32x4;
typedef __attribute__((ext_vector_type(8))) short short8v;
typedef __attribute__((ext_vector_type(8))) unsigned short ushort8v;

#define T_ROWS 16384
#define H_DIM  4096
#define E_NUM  64
#define TOPK   8

__device__ __forceinline__ unsigned short f2bf(float f) {
    unsigned int u = __float_as_uint(f);
    unsigned int r = (u + 0x7fffu + ((u >> 16) & 1u)) >> 16;  // RNE
    return (unsigned short)r;
}
__device__ __forceinline__ float bf2f(unsigned short h) {
    return __uint_as_float(((unsigned int)h) << 16);
}

__global__ __launch_bounds__(256) void router_kernel(
    const float* __restrict__ X, const float* __restrict__ W,
    const int* __restrict__ ids, int nids, float* __restrict__ out)
{
    const int tid = threadIdx.x;
    const int rb  = blockIdx.x * 64;   // 64 rows per workgroup

    __shared__ unsigned short XH[2][64][32], XL[2][64][32];
    __shared__ unsigned short WH[2][64][32], WL[2][64][32];
    __shared__ unsigned char  maskA[E_NUM];

    if (tid < E_NUM) maskA[tid] = 0;
    __syncthreads();
    if (tid < nids) { int e = ids[tid]; if (e >= 0 && e < E_NUM) maskA[e] = 1; }
    // maskA consumed only in epilogue; many __syncthreads before that.

    const int lane = tid & 63;
    const int wv   = tid >> 6;     // wave id -> rows wv*16 .. wv*16+15
    const int fr   = lane & 15;
    const int fq   = lane >> 4;

    f32x4 acc0 = {0.f,0.f,0.f,0.f};
    f32x4 acc1 = acc0, acc2 = acc0, acc3 = acc0;

    const int srow = tid >> 3;       // staging row (pass p adds 32)
    const int c8   = tid & 7;        // 8-float column chunk
    const int sub  = c8 >> 2;        // k32 subtile
    const int scol = (c8 & 3) * 8;   // column inside subtile

    float4 pX[2][2], pW[2][2];

    // ---- prefetch chunk 0 ----
    {
#pragma unroll
        for (int p = 0; p < 2; ++p) {
            const int row = srow + p * 32;
            const float4* gx = (const float4*)(X + (size_t)(rb + row) * H_DIM + c8 * 8);
            pX[p][0] = gx[0]; pX[p][1] = gx[1];
            const float4* gw = (const float4*)(W + (size_t)row * H_DIM + c8 * 8);
            pW[p][0] = gw[0]; pW[p][1] = gw[1];
        }
    }

    const int NCH = H_DIM / 64;
    for (int ch = 0; ch < NCH; ++ch) {
        __syncthreads();   // previous compute done reading LDS
        // ---- split to bf16 hi/lo and store to LDS ----
#pragma unroll
        for (int p = 0; p < 2; ++p) {
            const int row = srow + p * 32;
            {
                float v[8] = {pX[p][0].x, pX[p][0].y, pX[p][0].z, pX[p][0].w,
                              pX[p][1].x, pX[p][1].y, pX[p][1].z, pX[p][1].w};
                ushort8v hv, lv;
#pragma unroll
                for (int j = 0; j < 8; ++j) {
                    unsigned short h = f2bf(v[j]);
                    hv[j] = h;
                    lv[j] = f2bf(v[j] - bf2f(h));
                }
                *(ushort8v*)&XH[sub][row][scol] = hv;
                *(ushort8v*)&XL[sub][row][scol] = lv;
            }
            {
                float v[8] = {pW[p][0].x, pW[p][0].y, pW[p][0].z, pW[p][0].w,
                              pW[p][1].x, pW[p][1].y, pW[p][1].z, pW[p][1].w};
                ushort8v hv, lv;
#pragma unroll
                for (int j = 0; j < 8; ++j) {
                    unsigned short h = f2bf(v[j]);
                    hv[j] = h;
                    lv[j] = f2bf(v[j] - bf2f(h));
                }
                *(ushort8v*)&WH[sub][row][scol] = hv;
                *(ushort8v*)&WL[sub][row][scol] = lv;
            }
        }
        __syncthreads();
        // ---- issue next chunk's global loads (overlap with MFMA below) ----
        if (ch + 1 < NCH) {
            const int kb = (ch + 1) * 64;
#pragma unroll
            for (int p = 0; p < 2; ++p) {
                const int row = srow + p * 32;
                const float4* gx = (const float4*)(X + (size_t)(rb + row) * H_DIM + kb + c8 * 8);
                pX[p][0] = gx[0]; pX[p][1] = gx[1];
                const float4* gw = (const float4*)(W + (size_t)row * H_DIM + kb + c8 * 8);
                pW[p][0] = gw[0]; pW[p][1] = gw[1];
            }
        }
        // ---- MFMA: 3-product split-bf16, wave = 16 rows x 64 experts ----
#pragma unroll
        for (int ks = 0; ks < 2; ++ks) {
            short8v ah = *(const short8v*)&XH[ks][wv * 16 + fr][fq * 8];
            short8v al = *(const short8v*)&XL[ks][wv * 16 + fr][fq * 8];
            {
                short8v bh = *(const short8v*)&WH[ks][ 0 + fr][fq * 8];
                short8v bl = *(const short8v*)&WL[ks][ 0 + fr][fq * 8];
                acc0 = __builtin_amdgcn_mfma_f32_16x16x32_bf16(ah, bh, acc0, 0, 0, 0);
                acc0 = __builtin_amdgcn_mfma_f32_16x16x32_bf16(ah, bl, acc0, 0, 0, 0);
                acc0 = __builtin_amdgcn_mfma_f32_16x16x32_bf16(al, bh, acc0, 0, 0, 0);
            }
            {
                short8v bh = *(const short8v*)&WH[ks][16 + fr][fq * 8];
                short8v bl = *(const short8v*)&WL[ks][16 + fr][fq * 8];
                acc1 = __builtin_amdgcn_mfma_f32_16x16x32_bf16(ah, bh, acc1, 0, 0, 0);
                acc1 = __builtin_amdgcn_mfma_f32_16x16x32_bf16(ah, bl, acc1, 0, 0, 0);
                acc1 = __builtin_amdgcn_mfma_f32_16x16x32_bf16(al, bh, acc1, 0, 0, 0);
            }
            {
                short8v bh = *(const short8v*)&WH[ks][32 + fr][fq * 8];
                short8v bl = *(const short8v*)&WL[ks][32 + fr][fq * 8];
                acc2 = __builtin_amdgcn_mfma_f32_16x16x32_bf16(ah, bh, acc2, 0, 0, 0);
                acc2 = __builtin_amdgcn_mfma_f32_16x16x32_bf16(ah, bl, acc2, 0, 0, 0);
                acc2 = __builtin_amdgcn_mfma_f32_16x16x32_bf16(al, bh, acc2, 0, 0, 0);
            }
            {
                short8v bh = *(const short8v*)&WH[ks][48 + fr][fq * 8];
                short8v bl = *(const short8v*)&WL[ks][48 + fr][fq * 8];
                acc3 = __builtin_amdgcn_mfma_f32_16x16x32_bf16(ah, bh, acc3, 0, 0, 0);
                acc3 = __builtin_amdgcn_mfma_f32_16x16x32_bf16(ah, bl, acc3, 0, 0, 0);
                acc3 = __builtin_amdgcn_mfma_f32_16x16x32_bf16(al, bh, acc3, 0, 0, 0);
            }
        }
    }

    // ---- epilogue: mask, logits out (f32), softmax + top-8 + renorm ----
    // C/D layout (verified): col = lane&15, row_in_16 = (lane>>4)*4 + reg
    float* o_log = out;
    float* o_rw  = out + (size_t)T_ROWS * E_NUM;
    float* o_se  = o_rw + (size_t)T_ROWS * TOPK;

#pragma unroll
    for (int j = 0; j < 4; ++j) {
        const int grow = rb + wv * 16 + fq * 4 + j;
        float mv0 = maskA[ 0 + fr] ? acc0[j] : -10000.0f;
        float mv1 = maskA[16 + fr] ? acc1[j] : -10000.0f;
        float mv2 = maskA[32 + fr] ? acc2[j] : -10000.0f;
        float mv3 = maskA[48 + fr] ? acc3[j] : -10000.0f;
        o_log[(size_t)grow * 64 +  0 + fr] = mv0;
        o_log[(size_t)grow * 64 + 16 + fr] = mv1;
        o_log[(size_t)grow * 64 + 32 + fr] = mv2;
        o_log[(size_t)grow * 64 + 48 + fr] = mv3;

        // row max across the 16-lane group (each group = one row)
        float m = fmaxf(fmaxf(mv0, mv1), fmaxf(mv2, mv3));
#pragma unroll
        for (int off = 1; off < 16; off <<= 1) m = fmaxf(m, __shfl_xor(m, off));

        float tsum = 0.f, myv = 0.f;
        int   mye  = 0;
#pragma unroll
        for (int t = 0; t < TOPK; ++t) {
            float bv = mv0; int be = fr;
            if (mv1 > bv) { bv = mv1; be = 16 + fr; }
            if (mv2 > bv) { bv = mv2; be = 32 + fr; }
            if (mv3 > bv) { bv = mv3; be = 48 + fr; }
#pragma unroll
            for (int off = 1; off < 16; off <<= 1) {
                float ov = __shfl_xor(bv, off);
                int   oe = __shfl_xor(be, off);
                if (ov > bv || (ov == bv && oe < be)) { bv = ov; be = oe; }
            }
            float pv = expf(bv - m);
            tsum += pv;
            if (fr == t) { myv = pv; mye = be; }
            if ((be & 15) == fr) {       // exclude winner for next iteration
                int bn = be >> 4;
                if      (bn == 0) mv0 = -3.4e38f;
                else if (bn == 1) mv1 = -3.4e38f;
                else if (bn == 2) mv2 = -3.4e38f;
                else              mv3 = -3.4e38f;
            }
        }
        if (fr < TOPK) {
            o_rw[(size_t)grow * TOPK + fr] = myv / tsum;
            o_se[(size_t)grow * TOPK + fr] = (float)mye;
        }
    }
}

extern "C" void kernel_launch(void* const* d_in, const int* in_sizes, int n_in,
                              void* d_out, int out_size, void* d_ws, size_t ws_size,
                              hipStream_t stream) {
    const float* X   = (const float*)d_in[0];
    const float* W   = (const float*)d_in[1];
    const int*   ids = (const int*)d_in[2];
    const int    nids = in_sizes[2];
    float* out = (float*)d_out;

    dim3 grid(T_ROWS / 64), block(256);
    hipLaunchKernelGGL(router_kernel, grid, block, 0, stream, X, W, ids, nids, out);
}